// Round 11
// baseline (273.021 us; speedup 1.0000x reference)
//
#include <hip/hip_runtime.h>
#include <hip/hip_bf16.h>
#include <cstdint>
#include <cstddef>

#define D_MODEL 1024
#define HIDDEN 2048
#define E_ROUTED 14
#define E_TOT 16
#define NTOK 2048
#define NASSIGN 4096   // NTOK * TOP_K
#define NROWS 8192     // NASSIGN + 2*NTOK
#define GRID8 256      // persistent blocks, 1/CU, 32 per XCD

typedef __bf16 bf16x8 __attribute__((ext_vector_type(8)));
typedef float f32x4 __attribute__((ext_vector_type(4)));

static __device__ __forceinline__ unsigned short f2b(float f) {
  unsigned int u = __builtin_bit_cast(unsigned int, f);
  u += 0x7fffu + ((u >> 16) & 1u);   // RNE to bf16 (finite values only)
  return (unsigned short)(u >> 16);
}

// async global->LDS, 16B per lane; LDS dest = wave-uniform base + lane*16
#define ASYNC_COPY16(gptr, lptr)                                                        \
  __builtin_amdgcn_global_load_lds(                                                     \
      (const __attribute__((address_space(1))) unsigned int*)(gptr),                    \
      (__attribute__((address_space(3))) unsigned int*)(lptr), 16, 0, 0)

#define MEMBAR() asm volatile("" ::: "memory")

// ---------------- Router: logits -> softmax -> top2 -> renorm; write xhat bf16
__global__ __launch_bounds__(256) void router_kernel(
    const float* __restrict__ x, const float* __restrict__ rweight,
    int* __restrict__ topi, float* __restrict__ topw,
    unsigned short* __restrict__ xhat) {
  int n = blockIdx.x, tid = threadIdx.x;
  const float4 xv = reinterpret_cast<const float4*>(x + (size_t)n * D_MODEL)[tid];
  float ss = xv.x * xv.x + xv.y * xv.y + xv.z * xv.z + xv.w * xv.w;
  float lg[E_ROUTED];
#pragma unroll
  for (int e = 0; e < E_ROUTED; ++e) lg[e] = 0.f;
  const float xa[4] = {xv.x, xv.y, xv.z, xv.w};
#pragma unroll
  for (int i = 0; i < 4; ++i) {
    const float* rw = rweight + (size_t)(tid * 4 + i) * E_ROUTED;
    float xd = xa[i];
#pragma unroll
    for (int e = 0; e < E_ROUTED; ++e) lg[e] = fmaf(xd, rw[e], lg[e]);
  }
#pragma unroll
  for (int off = 32; off > 0; off >>= 1) {
    ss += __shfl_xor(ss, off);
#pragma unroll
    for (int e = 0; e < E_ROUTED; ++e) lg[e] += __shfl_xor(lg[e], off);
  }
  __shared__ float red[4][16];
  int wid = tid >> 6, lane = tid & 63;
  if (lane == 0) {
    red[wid][0] = ss;
#pragma unroll
    for (int e = 0; e < E_ROUTED; ++e) red[wid][1 + e] = lg[e];
  }
  __syncthreads();
  __shared__ float s_scale;
  if (tid == 0) {
    float fin[15];
    for (int v = 0; v < 15; ++v) fin[v] = red[0][v] + red[1][v] + red[2][v] + red[3][v];
    s_scale = rsqrtf(fin[0] * (1.f / D_MODEL) + 1.1920929e-07f);
    float mx = fin[1];
    for (int e = 1; e < E_ROUTED; ++e) mx = fmaxf(mx, fin[1 + e]);
    float p[E_ROUTED]; float Z = 0.f;
    for (int e = 0; e < E_ROUTED; ++e) { p[e] = __expf(fin[1 + e] - mx); Z += p[e]; }
    int i0 = 0; float v0 = p[0];
    for (int e = 1; e < E_ROUTED; ++e) if (p[e] > v0) { v0 = p[e]; i0 = e; }
    int i1 = (i0 == 0) ? 1 : 0; float v1 = p[i1];
    for (int e = 0; e < E_ROUTED; ++e) if (e != i0 && p[e] > v1) { v1 = p[e]; i1 = e; }
    v0 /= Z; v1 /= Z;
    float inv = 1.f / (v0 + v1 + 1e-9f);
    topi[2 * n] = i0; topi[2 * n + 1] = i1;
    topw[2 * n] = v0 * inv; topw[2 * n + 1] = v1 * inv;
  }
  __syncthreads();
  float sc = s_scale;
  ushort4 hx;
  hx.x = f2b(xv.x * sc); hx.y = f2b(xv.y * sc);
  hx.z = f2b(xv.z * sc); hx.w = f2b(xv.w * sc);
  reinterpret_cast<ushort4*>(xhat + (size_t)n * D_MODEL)[tid] = hx;
}

// ---------------- Count experts -> offsets + cursors + unified GEMM work plan
// Item counts use 256-row m-tiles; per group items = mt * 8 for BOTH GEMMs
// (G1: 8 n-panels of 256; G2: 4 n-panels x 2 k-slices).
__global__ __launch_bounds__(256) void count_kernel(const int* __restrict__ topi,
                                                    int* __restrict__ goff,
                                                    int* __restrict__ cursor,
                                                    int* __restrict__ wbase) {
  __shared__ int cnt[E_ROUTED];
  int tid = threadIdx.x;
  if (tid < E_ROUTED) cnt[tid] = 0;
  __syncthreads();
  for (int i = tid; i < NASSIGN; i += 256) atomicAdd(&cnt[topi[i]], 1);
  __syncthreads();
  if (tid == 0) {
    int acc = 0;
    for (int e = 0; e < E_ROUTED; ++e) { goff[e] = acc; cursor[e] = acc; acc += cnt[e]; }
    goff[E_ROUTED] = acc;   // == NASSIGN
    int b = 0;
    for (int g = 0; g < E_TOT; ++g) {
      wbase[g] = b;
      int c = (g < E_ROUTED) ? cnt[g] : NTOK;
      b += ((c + 255) >> 8) * 8;
    }
    wbase[E_TOT] = b;
  }
}

// ---------------- Scatter assignments into per-expert compact rows
__global__ __launch_bounds__(256) void scatter_kernel(
    const int* __restrict__ topi, const float* __restrict__ topw,
    int* __restrict__ cursor, int* __restrict__ row_token,
    float* __restrict__ row_gate, int* __restrict__ token_rows) {
  int i = blockIdx.x * 256 + threadIdx.x;
  if (i >= NASSIGN) return;
  int e = topi[i];
  int pos = atomicAdd(&cursor[e], 1);
  row_token[pos] = i >> 1;
  row_gate[pos] = topw[i];
  token_rows[i] = pos;
}

// ---------------- Transpose + fp32->bf16 convert: W[e][K][N] -> Wt[e][N][K]
// (R2-verified version.) SCALE: fold rms weight (per-k scale) into W1.
template <int K, int N, bool SCALE>
__global__ __launch_bounds__(256) void convT_kernel(
    const float* __restrict__ Wr, const float* __restrict__ Ws,
    const float* __restrict__ RWr, const float* __restrict__ RWs,
    unsigned short* __restrict__ outT) {
  __shared__ float tile[64][65];
  int g = blockIdx.z;
  const float* src = (g < E_ROUTED) ? Wr + (size_t)g * K * N
                                    : Ws + (size_t)(g - E_ROUTED) * K * N;
  const float* rw = nullptr;
  if constexpr (SCALE)
    rw = (g < E_ROUTED) ? RWr + (size_t)g * K : RWs + (size_t)(g - E_ROUTED) * K;
  int k0 = blockIdx.y * 64, nn0 = blockIdx.x * 64;
  int t = threadIdx.x;
  int kk = t >> 4, nc = (t & 15) * 4;
#pragma unroll
  for (int j = 0; j < 4; ++j) {
    int k = kk + j * 16;
    float4 v = *(const float4*)(src + (size_t)(k0 + k) * N + nn0 + nc);
    float s = 1.f;
    if constexpr (SCALE) s = rw[k0 + k];
    tile[k][nc]     = v.x * s;
    tile[k][nc + 1] = v.y * s;
    tile[k][nc + 2] = v.z * s;
    tile[k][nc + 3] = v.w * s;
  }
  __syncthreads();
  int k8 = (t & 7) * 8;
#pragma unroll
  for (int p = 0; p < 2; ++p) {
    int n = (t >> 3) + p * 32;
    uint4 pk;
    pk.x = (unsigned)f2b(tile[k8 + 0][n]) | ((unsigned)f2b(tile[k8 + 1][n]) << 16);
    pk.y = (unsigned)f2b(tile[k8 + 2][n]) | ((unsigned)f2b(tile[k8 + 3][n]) << 16);
    pk.z = (unsigned)f2b(tile[k8 + 4][n]) | ((unsigned)f2b(tile[k8 + 5][n]) << 16);
    pk.w = (unsigned)f2b(tile[k8 + 6][n]) | ((unsigned)f2b(tile[k8 + 7][n]) << 16);
    *(uint4*)(outT + ((size_t)g * N + nn0 + n) * K + k0 + k8) = pk;
  }
}

// ---------------- Grouped GEMM, 256x256 tile, 8 waves, fine-phase pipeline
// (T3+T4): 4 phases/K-tile, counted vmcnt (never 0 in steady state), dbuf
// 128KB LDS as 4x16KB K-half planes per buffer, setprio around MFMA clusters.
// Persistent 256 blocks over XCD-chunked m-inner work list (R10 scheme).
// G1: h = silu(xhat[token] @ W1t[g]^T); G2 (split-K 2): y[ksl] = partial.
template <bool G1>
__global__ __launch_bounds__(512, 2) void ffn_gemm8(
    const int* __restrict__ goff, const int* __restrict__ wbase,
    const int* __restrict__ row_token, const float* __restrict__ row_gate,
    const unsigned short* __restrict__ Abase,
    const unsigned short* __restrict__ Wt,
    unsigned short* __restrict__ Hout, float* __restrict__ Yout) {
  constexpr int AKS  = G1 ? D_MODEL : HIDDEN;   // A row k-stride (elements)
  constexpr int BKS  = G1 ? D_MODEL : HIDDEN;   // Wt row k-stride
  constexpr int NTOT = G1 ? HIDDEN : D_MODEL;   // B n-rows per expert
  constexpr int NT = 16;                        // K-tiles of 64 over KLEN=1024

  // buffers: [2][ A-k0 16K | A-k1 16K | B-k0 16K | B-k1 16K ]
  __shared__ __align__(16) char smem[2][65536];
  __shared__ int swb[E_TOT + 1];
  __shared__ int sgoff[E_ROUTED + 1];

  int t = threadIdx.x, lane = t & 63, wid = t >> 6;
  if (t <= E_TOT) swb[t] = wbase[t];
  if (t >= 32 && t <= 32 + E_ROUTED) sgoff[t - 32] = goff[t - 32];
  __syncthreads();

  int xcd = blockIdx.x & 7, slot = blockIdx.x >> 3;   // 32 slots/XCD
  int total = swb[E_TOT];
  int chunk = (total + 7) >> 3;
  int cend = min((xcd + 1) * chunk, total);

  int wm = wid >> 2, wn = wid & 3;   // wave tile: rows wm*128, cols wn*64
  int l15 = lane & 15;
  // staging: per plane, wave covers chunks {wid, wid+8}; lane -> row (lane>>2),
  // slot (lane&3); source slot pre-XOR'd by (row&3)=(lane>>2)&3  [rule 21]
  int srow[2] = {wid * 16 + (lane >> 2), (8 + wid) * 16 + (lane >> 2)};
  int soff = (((lane & 3) ^ ((lane >> 2) & 3)) << 4);

  // LDS frag readers (plane layout; read-side XOR matches staged pre-swizzle)
  auto lda = [&](int p, int ks, int rr) -> bf16x8 {
    return *(const bf16x8*)(smem[p] + ks * 16384 + rr * 64 +
                            ((((lane >> 4) ^ (rr & 3))) << 4));
  };
  auto ldb = [&](int p, int ks, int rr) -> bf16x8 {
    return *(const bf16x8*)(smem[p] + 32768 + ks * 16384 + rr * 64 +
                            ((((lane >> 4) ^ (rr & 3))) << 4));
  };

  for (int c = xcd * chunk + slot; c < cend; c += (GRID8 >> 3)) {
    // ---- decode item c -> (g, n-panel, m-tile [, k-slice])
    int g = 0;
    while (swb[g + 1] <= c) ++g;
    int grpStart, cnt;
    if (g < E_ROUTED) { grpStart = sgoff[g]; cnt = sgoff[g + 1] - sgoff[g]; }
    else { grpStart = NASSIGN + (g - E_ROUTED) * NTOK; cnt = NTOK; }
    int mtg = (cnt + 255) >> 8;
    int r = c - swb[g];
    int myb, nxb, ksl = 0;
    if constexpr (G1) { nxb = r / mtg; myb = r - nxb * mtg; }
    else { ksl = r / (4 * mtg); int r2 = r - ksl * 4 * mtg; nxb = r2 / mtg; myb = r2 - nxb * mtg; }
    int m0 = myb * 256, n0 = nxb * 256, kOff = ksl * 1024;

    // ---- staging source pointers (advance +128B per K-tile; +64B for k-half1)
    const char* aS[2];
    const char* bS[2];
#pragma unroll
    for (int i = 0; i < 2; ++i) {
      int rIdx = m0 + srow[i]; if (rIdx >= cnt) rIdx = cnt - 1;
      int sR;
      if constexpr (G1) sR = (g < E_ROUTED) ? row_token[grpStart + rIdx] : rIdx;
      else sR = grpStart + rIdx;
      aS[i] = (const char*)(Abase + (size_t)sR * AKS + kOff) + soff;
      bS[i] = (const char*)(Wt + ((size_t)g * NTOT + n0 + srow[i]) * BKS + kOff) + soff;
    }

    f32x4 acc[8][4];
#pragma unroll
    for (int m = 0; m < 8; ++m)
#pragma unroll
      for (int n = 0; n < 4; ++n)
#pragma unroll
        for (int cc = 0; cc < 4; ++cc) acc[m][n][cc] = 0.f;

    // stage one 16KB plane (mat 0=A,1=B; k-half h) of next tile into buf q
    auto STAGE = [&](int q, int mat, int h) {
      char* dst = smem[q] + mat * 32768 + h * 16384 + wid * 1024;
      const char* s0 = (mat ? bS[0] : aS[0]) + h * 64;
      const char* s1 = (mat ? bS[1] : aS[1]) + h * 64;
      ASYNC_COPY16(s0, dst);
      ASYNC_COPY16(s1, dst + 8192);
    };

    // prologue: tile 0 into buf 0 (k0 planes FIRST -> vmcnt(4) invariant)
    STAGE(0, 0, 0); STAGE(0, 1, 0); STAGE(0, 0, 1); STAGE(0, 1, 1);
#pragma unroll
    for (int i = 0; i < 2; ++i) { aS[i] += 128; bS[i] += 128; }

    for (int kt = 0; kt < NT; ++kt) {
      int p = kt & 1, q = p ^ 1;
      bool st = (kt + 1 < NT);
      bf16x8 bfr[4];

#define PHASE(KS, MH, SMAT, SH, VM)                                              \
      { if ((VM) == 0) asm volatile("s_waitcnt vmcnt(0)" ::: "memory");          \
        else if ((VM) > 0) asm volatile("s_waitcnt vmcnt(4)" ::: "memory");      \
        __builtin_amdgcn_s_barrier();                                            \
        MEMBAR();                                                                \
        if (MH == 0) {                                                           \
          _Pragma("unroll") for (int nf = 0; nf < 4; ++nf)                       \
            bfr[nf] = ldb(p, KS, wn * 64 + nf * 16 + l15);                       \
        }                                                                        \
        bf16x8 a_[4];                                                            \
        _Pragma("unroll") for (int mf = 0; mf < 4; ++mf)                         \
          a_[mf] = lda(p, KS, wm * 128 + MH * 64 + mf * 16 + l15);               \
        if (st) STAGE(q, SMAT, SH);                                              \
        __builtin_amdgcn_s_setprio(1);                                           \
        _Pragma("unroll") for (int mf = 0; mf < 4; ++mf)                         \
          _Pragma("unroll") for (int nf = 0; nf < 4; ++nf)                       \
            acc[MH * 4 + mf][nf] = __builtin_amdgcn_mfma_f32_16x16x32_bf16(     \
                a_[mf], bfr[nf], acc[MH * 4 + mf][nf], 0, 0, 0);                 \
        __builtin_amdgcn_s_setprio(0); }

      PHASE(0, 0, 0, 0, 4)               // needs kt k0-planes (oldest 4); stage A-k0
      PHASE(0, 1, 1, 0, -1)              // stage B-k0
      PHASE(1, 0, 0, 1, (st ? 4 : 0))    // needs kt k1-planes; stage A-k1
      PHASE(1, 1, 1, 1, -1)              // stage B-k1
#undef PHASE

      if (st) {
#pragma unroll
        for (int i = 0; i < 2; ++i) { aS[i] += 128; bS[i] += 128; }
      }
    }

    // ---- epilogue. C/D: col = lane&15, row = (lane>>4)*4 + j  [m89-verified]
    int lr = (lane >> 4) * 4;
#pragma unroll
    for (int mf = 0; mf < 8; ++mf) {
      int rloc = m0 + wm * 128 + mf * 16 + lr;
#pragma unroll
      for (int j = 0; j < 4; ++j) {
        if (rloc + j < cnt) {
          size_t rg = (size_t)(grpStart + rloc + j);
          if constexpr (G1) {
#pragma unroll
            for (int nf = 0; nf < 4; ++nf) {
              float v = acc[mf][nf][j];
              float sv = v / (1.f + __expf(-v));
              Hout[rg * HIDDEN + (n0 + wn * 64 + nf * 16 + l15)] = f2b(sv);
            }
          } else {
            float gate = 1.f;
            if (g < E_ROUTED) gate = row_gate[rg];
            float* yo = Yout + (size_t)ksl * NROWS * D_MODEL;
#pragma unroll
            for (int nf = 0; nf < 4; ++nf)
              yo[rg * D_MODEL + (n0 + wn * 64 + nf * 16 + l15)] = acc[mf][nf][j] * gate;
          }
        }
      }
    }
  }
}

// ---------------- Combine: out[n] = sum over 2 k-slices of (y[a0]+y[a1]+y[s0]+y[s1])
__global__ __launch_bounds__(256) void combine_kernel(
    const float* __restrict__ y, const int* __restrict__ token_rows,
    float* __restrict__ out) {
  int n = blockIdx.x, tid = threadIdx.x;
  int a0 = token_rows[2 * n], a1 = token_rows[2 * n + 1];
  float4 r = {0.f, 0.f, 0.f, 0.f};
#pragma unroll
  for (int ks = 0; ks < 2; ++ks) {
    const float* yb = y + (size_t)ks * NROWS * D_MODEL;
    float4 a = reinterpret_cast<const float4*>(yb + (size_t)a0 * D_MODEL)[tid];
    float4 b = reinterpret_cast<const float4*>(yb + (size_t)a1 * D_MODEL)[tid];
    float4 c = reinterpret_cast<const float4*>(yb + (size_t)(NASSIGN + n) * D_MODEL)[tid];
    float4 d = reinterpret_cast<const float4*>(yb + (size_t)(NASSIGN + NTOK + n) * D_MODEL)[tid];
    r.x += a.x + b.x + c.x + d.x;
    r.y += a.y + b.y + c.y + d.y;
    r.z += a.z + b.z + c.z + d.z;
    r.w += a.w + b.w + c.w + d.w;
  }
  reinterpret_cast<float4*>(out + (size_t)n * D_MODEL)[tid] = r;
}

extern "C" void kernel_launch(void* const* d_in, const int* in_sizes, int n_in,
                              void* d_out, int out_size, void* d_ws, size_t ws_size,
                              hipStream_t stream) {
  const float* x        = (const float*)d_in[0];
  const float* router_w = (const float*)d_in[1];
  const float* rms_w    = (const float*)d_in[2];
  const float* w1       = (const float*)d_in[3];
  const float* w2       = (const float*)d_in[4];
  const float* rms_w_s  = (const float*)d_in[5];
  const float* w1_s    = (const float*)d_in[6];
  const float* w2_s    = (const float*)d_in[7];
  float* out = (float*)d_out;

  char* ws = (char*)d_ws;
  unsigned short* xhat = (unsigned short*)ws;                         // 4 MB
  unsigned short* h    = (unsigned short*)(ws + ((size_t)4 << 20));   // 32 MB
  float* y             = (float*)(ws + ((size_t)36 << 20));           // 2x32 MB; slice1 overlays w1t (dead after G1)
  unsigned short* w1t  = (unsigned short*)(ws + ((size_t)68 << 20));  // 64 MB [16][H][D]
  unsigned short* w2t  = (unsigned short*)(ws + ((size_t)132 << 20)); // 64 MB [16][D][H]
  char* meta = ws + ((size_t)196 << 20);
  int*   topi       = (int*)(meta);
  float* topw       = (float*)(meta + (16 << 10));
  int*   row_token  = (int*)(meta + (32 << 10));
  float* row_gate   = (float*)(meta + (48 << 10));
  int*   token_rows = (int*)(meta + (64 << 10));
  int*   goff       = (int*)(meta + (80 << 10));          // 17 ints
  int*   cursor     = (int*)(meta + (80 << 10) + 128);    // 14 ints
  int*   wbase      = (int*)(meta + (80 << 10) + 256);    // 17 ints

  router_kernel<<<NTOK, 256, 0, stream>>>(x, router_w, topi, topw, xhat);
  count_kernel<<<1, 256, 0, stream>>>(topi, goff, cursor, wbase);
  scatter_kernel<<<NASSIGN / 256, 256, 0, stream>>>(topi, topw, cursor, row_token,
                                                    row_gate, token_rows);
  convT_kernel<D_MODEL, HIDDEN, true><<<dim3(HIDDEN / 64, D_MODEL / 64, E_TOT), 256, 0, stream>>>(
      w1, w1_s, rms_w, rms_w_s, w1t);
  convT_kernel<HIDDEN, D_MODEL, false><<<dim3(D_MODEL / 64, HIDDEN / 64, E_TOT), 256, 0, stream>>>(
      w2, w2_s, nullptr, nullptr, w2t);
  ffn_gemm8<true><<<GRID8, 512, 0, stream>>>(
      goff, wbase, row_token, row_gate, xhat, w1t, h, nullptr);
  ffn_gemm8<false><<<GRID8, 512, 0, stream>>>(
      goff, wbase, row_token, row_gate, h, w2t, nullptr, y);
  combine_kernel<<<NTOK, 256, 0, stream>>>(y, token_rows, out);
}